// Round 1
// baseline (12969.139 us; speedup 1.0000x reference)
//
#include <hip/hip_runtime.h>
#include <stdint.h>

#define TT 2048
#define BB 64
#define HH 256

// ws float-word layout
#define WIHT_OFF 0          // W_ih^T : 256 tokens x 1024 gate-rows
#define BIAS_OFF 262144     // b_ih + b_hh : 1024
#define HBUF_OFF 263168     // h double buffer: 2 x 64 x 256
#define FLAG_OFF 295936     // 256 uint flags (one per WG)
#define WS_TOT   296192

#define LOGITS   33554432   // 64*2048*256

// ---------------- K1: prep (transpose W_ih, fuse biases, zero h/flags) ---------
__global__ __launch_bounds__(256, 1) void k_prep(const float* __restrict__ W_ih,
                                                 const float* __restrict__ b_ih,
                                                 const float* __restrict__ b_hh,
                                                 float* ws_f) {
    int idx = blockIdx.x * 256 + threadIdx.x;
    if (idx < 262144) {
        int v = idx >> 10, r = idx & 1023;
        ws_f[WIHT_OFF + idx] = W_ih[r * 256 + v];
    } else if (idx < 263168) {
        int r = idx - 262144;
        ws_f[idx] = b_ih[r] + b_hh[r];
    } else if (idx < 295936) {
        ws_f[idx] = 0.0f;                 // h double buffer -> 0
    } else if (idx < 296192) {
        ((unsigned*)ws_f)[idx] = 0u;      // flags -> 0
    }
}

// ---------------- K2: persistent LSTM recurrence ------------------------------
// 256 WGs x 256 threads. WG (b,q) owns hidden units j in [q*64, q*64+64) of
// batch b: 256 gate rows, each thread holds one full W_hh row (256 f32) in
// VGPRs (256 VGPRs -> 1 wave/SIMD -> exactly 1 WG per CU, all 256 co-resident).
// Per step: h exchange among the 4 WGs of a batch via LLC + release/acquire
// flags, double-buffered by step parity.
__global__ __launch_bounds__(256, 1) void k_lstm(const int* __restrict__ x,
                                                 const float* __restrict__ W_hh,
                                                 float* ws_f,
                                                 float* out) {
    const int tid = threadIdx.x;
    const int bid = blockIdx.x;
    // co-locate the 4 WGs of a batch on one XCD under the blk%8 heuristic
    const int xcd  = bid & 7;
    const int slot = bid >> 3;          // 32 slots per xcd
    const int b = xcd + 8 * (slot >> 2);
    const int q = slot & 3;
    const int u  = tid & 63;
    const int gt = tid >> 6;            // 0=i 1=f 2=g 3=o
    const int j  = q * 64 + u;
    const int r  = gt * 256 + j;        // gate row in [0,1024)

    __shared__ alignas(16) float hin[256];
    __shared__ float gbuf[256];

    // W_hh row r -> registers (one-time; L2/LLC absorbs the 64 MB broadcast)
    float4 w4[64];
    {
        const float4* wr = (const float4*)(W_hh + (size_t)r * 256);
#pragma unroll
        for (int k = 0; k < 64; ++k) w4[k] = wr[k];
    }
    const float bias_r = ws_f[BIAS_OFF + r];
    float* hglob = ws_f + HBUF_OFF;
    unsigned* flags = (unsigned*)ws_f + FLAG_OFF;
    const int* xrow = x + b * TT;

    float c_state = 0.0f;               // live only in tid<64 (wave 0)

    for (int t = 0; t < TT; ++t) {
        const int p = t & 1;
        // issue the x-projection gather BEFORE the spin: latency (and the
        // acquire's L2-inv refetch) hides under the flag wait
        int tok = xrow[t];
        float xw = ws_f[WIHT_OFF + tok * 1024 + r] + bias_r;

        if (tid < 4) {
            unsigned tu = (unsigned)t;
            int guard = 0;
            while (__hip_atomic_load(&flags[b * 4 + tid], __ATOMIC_ACQUIRE,
                                     __HIP_MEMORY_SCOPE_AGENT) < tu) {
                if (++guard > (1 << 17)) break;   // anti-hang safety valve
            }
        }
        __syncthreads();
        // gather full h (written by the 4 peer WGs last step) into LDS
        hin[tid] = hglob[p * (BB * HH) + b * HH + tid];
        __syncthreads();

        // gate pre-activation: dot(W_hh[r,:], h) with 4 accumulator chains
        const float4* hv = (const float4*)hin;
        float a0 = 0.f, a1 = 0.f, a2 = 0.f, a3 = 0.f;
#pragma unroll
        for (int k = 0; k < 64; ++k) {
            float4 hh = hv[k];
            a0 += w4[k].x * hh.x;
            a1 += w4[k].y * hh.y;
            a2 += w4[k].z * hh.z;
            a3 += w4[k].w * hh.w;
        }
        float gate = xw + ((a0 + a1) + (a2 + a3));
        float act = (gt == 2) ? tanhf(gate)
                              : 1.0f / (1.0f + __expf(-gate));  // wave-uniform branch
        gbuf[tid] = act;
        __syncthreads();

        if (tid < 64) {                  // wave 0 combines gates, owns c
            float ig = gbuf[tid], fg = gbuf[64 + tid];
            float gg = gbuf[128 + tid], og = gbuf[192 + tid];
            c_state = fg * c_state + ig * gg;
            float hval = og * tanhf(c_state);
            hglob[(p ^ 1) * (BB * HH) + b * HH + j] = hval;          // exchange slot
            out[((size_t)(b * TT + t) << 8) + j] = hval;             // h history
            if (t == TT - 1) {
                out[LOGITS + b * HH + j] = hval;                     // h_n
                out[LOGITS + BB * HH + b * HH + j] = c_state;        // c_n
            }
        }
        if (tid == 0)
            __hip_atomic_store(&flags[b * 4 + q], (unsigned)(t + 1),
                               __ATOMIC_RELEASE, __HIP_MEMORY_SCOPE_AGENT);
    }
}

// ---------------- K3: FC epilogue, in-place over the logits region ------------
// logits[n,:] = h[n,:] @ fc_W^T + fc_b. Each block: 64 rows staged to LDS
// (fully read before any write -> in-place safe), thread v holds fc_W row v
// (256 f32) in VGPRs.
__global__ __launch_bounds__(256, 1) void k_fc(const float* __restrict__ fc_W,
                                               const float* __restrict__ fc_b,
                                               float* out) {
    __shared__ alignas(16) float ht[64][256];
    const int tid = threadIdx.x;
    const size_t base = (size_t)blockIdx.x * 64;
    for (int i = 0; i < 64; ++i)
        ht[i][tid] = out[(base + i) * 256 + tid];

    float4 w4[64];
    const float4* wr = (const float4*)(fc_W + (size_t)tid * 256);
#pragma unroll
    for (int k = 0; k < 64; ++k) w4[k] = wr[k];
    const float bias = fc_b[tid];
    __syncthreads();

    for (int m = 0; m < 64; ++m) {
        const float4* hv = (const float4*)ht[m];
        float a0 = 0.f, a1 = 0.f, a2 = 0.f, a3 = 0.f;
#pragma unroll
        for (int k = 0; k < 64; ++k) {
            float4 hh = hv[k];
            a0 += w4[k].x * hh.x;
            a1 += w4[k].y * hh.y;
            a2 += w4[k].z * hh.z;
            a3 += w4[k].w * hh.w;
        }
        out[(base + m) * 256 + tid] = bias + ((a0 + a1) + (a2 + a3));
    }
}

// ---------------- launch ------------------------------------------------------
extern "C" void kernel_launch(void* const* d_in, const int* in_sizes, int n_in,
                              void* d_out, int out_size, void* d_ws, size_t ws_size,
                              hipStream_t stream) {
    const int*   x    = (const int*)d_in[0];
    const float* W_ih = (const float*)d_in[1];
    const float* W_hh = (const float*)d_in[2];
    const float* b_ih = (const float*)d_in[3];
    const float* b_hh = (const float*)d_in[4];
    const float* fc_W = (const float*)d_in[5];
    const float* fc_b = (const float*)d_in[6];
    float* out  = (float*)d_out;
    float* ws_f = (float*)d_ws;

    k_prep<<<(WS_TOT + 255) / 256, 256, 0, stream>>>(W_ih, b_ih, b_hh, ws_f);
    k_lstm<<<256, 256, 0, stream>>>(x, W_hh, ws_f, out);
    k_fc<<<2048, 256, 0, stream>>>(fc_W, fc_b, out);
}

// Round 2
// 7371.251 us; speedup vs baseline: 1.7594x; 1.7594x over previous
//
#include <hip/hip_runtime.h>
#include <stdint.h>

#define TT 2048
#define BB 64
#define HH 256

// ws float-word layout
#define WIHT_OFF 0          // W_ih^T : 256 tokens x 1024 gate-rows
#define BIAS_OFF 262144     // b_ih + b_hh : 1024
#define HBUF_OFF 263168     // packed h exchange: 2 slots x 64 x 256 x uint64 (epoch<<32|bits)
#define WS_TOT   328704     // floats

#define LOGITS   33554432   // 64*2048*256

// ---------------- K1: prep (transpose W_ih, fuse biases, zero exchange buf) ---
__global__ __launch_bounds__(256, 1) void k_prep(const float* __restrict__ W_ih,
                                                 const float* __restrict__ b_ih,
                                                 const float* __restrict__ b_hh,
                                                 float* ws_f) {
    int idx = blockIdx.x * 256 + threadIdx.x;
    if (idx < 262144) {
        int v = idx >> 10, r = idx & 1023;
        ws_f[WIHT_OFF + idx] = W_ih[r * 256 + v];
    } else if (idx < 263168) {
        int r = idx - 262144;
        ws_f[idx] = b_ih[r] + b_hh[r];
    } else if (idx < WS_TOT) {
        ws_f[idx] = 0.0f;   // exchange slots: epoch=0, value=0 (kills 0xAA poison)
    }
}

// ---------------- K2: persistent LSTM recurrence ------------------------------
// 256 WGs x 256 threads; WG (b,q) owns hidden units [q*64,q*64+64) of batch b
// (256 gate rows, one full f32 W_hh row per thread in VGPR/AGPR).
// Cross-WG h exchange: RELAXED agent-scope 64-bit atomics carrying
// (epoch<<32 | float_bits). No acquire/release -> no buffer_inv / buffer_wbl2
// per step (round 1's 6us/step was L2 flush/invalidate traffic from the
// acquire-polling loop). Payload travels inside the atomic => fence-free.
// Double-buffered by step parity (peer skew provably <=1 step).
__global__ __launch_bounds__(256, 1) void k_lstm(const int* __restrict__ x,
                                                 const float* __restrict__ W_hh,
                                                 float* ws_f,
                                                 float* out) {
    const int tid = threadIdx.x;
    const int bid = blockIdx.x;
    // co-locate the 4 WGs of a batch on one XCD under the blk%8 heuristic
    const int xcd  = bid & 7;
    const int slot = bid >> 3;
    const int b = xcd + 8 * (slot >> 2);
    const int q = slot & 3;
    const int u  = tid & 63;
    const int gt = tid >> 6;            // 0=i 1=f 2=g 3=o
    const int j  = q * 64 + u;
    const int r  = gt * 256 + j;        // gate row in [0,1024)

    __shared__ alignas(16) float hin[256];
    __shared__ float gbuf[256];
    __shared__ float hloc[64];          // own quarter's h from previous step

    // W_hh row r -> registers (one-time)
    float4 w4[64];
    {
        const float4* wr = (const float4*)(W_hh + (size_t)r * 256);
#pragma unroll
        for (int k = 0; k < 64; ++k) w4[k] = wr[k];
    }
    const float bias_r = ws_f[BIAS_OFF + r];
    unsigned long long* hbuf = (unsigned long long*)(ws_f + HBUF_OFF);
    const int* xrow = x + b * TT;
    const bool own = (tid >> 6) == q;   // element tid belongs to our quarter

    if (own) hloc[tid & 63] = 0.0f;     // h(0) = 0
    float c_state = 0.0f;               // live in tid<64 (wave 0)
    __syncthreads();

    for (int t = 0; t < TT; ++t) {
        const int p = t & 1;
        // issue x-projection gather before the poll so its latency hides
        int tok = xrow[t];
        float xw = ws_f[WIHT_OFF + tok * 1024 + r] + bias_r;

        // gather h(t): own quarter from LDS, remote quarters via relaxed
        // agent atomics polled directly on the packed (epoch|value) word
        if (own) {
            hin[tid] = hloc[tid & 63];
        } else {
            unsigned long long* src = hbuf + (size_t)p * (BB * HH) + b * HH + tid;
            unsigned long long v;
            int guard = 0;
            do {
                v = __hip_atomic_load(src, __ATOMIC_RELAXED, __HIP_MEMORY_SCOPE_AGENT);
            } while ((unsigned)(v >> 32) != (unsigned)t && ++guard < (1 << 20));
            hin[tid] = __uint_as_float((unsigned)v);
        }
        __syncthreads();

        // gate pre-activation: dot(W_hh[r,:], h) with 4 accumulator chains
        const float4* hv = (const float4*)hin;
        float a0 = 0.f, a1 = 0.f, a2 = 0.f, a3 = 0.f;
#pragma unroll
        for (int k = 0; k < 64; ++k) {
            float4 hh = hv[k];
            a0 += w4[k].x * hh.x;
            a1 += w4[k].y * hh.y;
            a2 += w4[k].z * hh.z;
            a3 += w4[k].w * hh.w;
        }
        float gate = xw + ((a0 + a1) + (a2 + a3));
        float act = (gt == 2) ? tanhf(gate)
                              : 1.0f / (1.0f + __expf(-gate));  // wave-uniform branch
        gbuf[tid] = act;
        __syncthreads();

        if (tid < 64) {                  // wave 0 combines gates, owns c
            float ig = gbuf[tid], fg = gbuf[64 + tid];
            float gg = gbuf[128 + tid], og = gbuf[192 + tid];
            c_state = fg * c_state + ig * gg;
            float hval = og * tanhf(c_state);
            // critical-path store first: packed (epoch+1 | bits) to parity slot
            unsigned long long pv =
                ((unsigned long long)(unsigned)(t + 1) << 32) |
                (unsigned long long)__float_as_uint(hval);
            __hip_atomic_store(hbuf + (size_t)((t + 1) & 1) * (BB * HH) + b * HH + j,
                               pv, __ATOMIC_RELAXED, __HIP_MEMORY_SCOPE_AGENT);
            hloc[tid] = hval;
            out[((size_t)(b * TT + t) << 8) + j] = hval;             // h history
            if (t == TT - 1) {
                out[LOGITS + b * HH + j] = hval;                     // h_n
                out[LOGITS + BB * HH + b * HH + j] = c_state;        // c_n
            }
        }
        __syncthreads();                 // protects hloc/gbuf/hin for next iter
    }
}

// ---------------- K3: FC epilogue, in-place over the logits region ------------
__global__ __launch_bounds__(256, 1) void k_fc(const float* __restrict__ fc_W,
                                               const float* __restrict__ fc_b,
                                               float* out) {
    __shared__ alignas(16) float ht[64][256];
    const int tid = threadIdx.x;
    const size_t base = (size_t)blockIdx.x * 64;
    for (int i = 0; i < 64; ++i)
        ht[i][tid] = out[(base + i) * 256 + tid];

    float4 w4[64];
    const float4* wr = (const float4*)(fc_W + (size_t)tid * 256);
#pragma unroll
    for (int k = 0; k < 64; ++k) w4[k] = wr[k];
    const float bias = fc_b[tid];
    __syncthreads();

    for (int m = 0; m < 64; ++m) {
        const float4* hv = (const float4*)ht[m];
        float a0 = 0.f, a1 = 0.f, a2 = 0.f, a3 = 0.f;
#pragma unroll
        for (int k = 0; k < 64; ++k) {
            float4 hh = hv[k];
            a0 += w4[k].x * hh.x;
            a1 += w4[k].y * hh.y;
            a2 += w4[k].z * hh.z;
            a3 += w4[k].w * hh.w;
        }
        out[(base + m) * 256 + tid] = bias + ((a0 + a1) + (a2 + a3));
    }
}

// ---------------- launch ------------------------------------------------------
extern "C" void kernel_launch(void* const* d_in, const int* in_sizes, int n_in,
                              void* d_out, int out_size, void* d_ws, size_t ws_size,
                              hipStream_t stream) {
    const int*   x    = (const int*)d_in[0];
    const float* W_ih = (const float*)d_in[1];
    const float* W_hh = (const float*)d_in[2];
    const float* b_ih = (const float*)d_in[3];
    const float* b_hh = (const float*)d_in[4];
    const float* fc_W = (const float*)d_in[5];
    const float* fc_b = (const float*)d_in[6];
    float* out  = (float*)d_out;
    float* ws_f = (float*)d_ws;

    k_prep<<<(WS_TOT + 255) / 256, 256, 0, stream>>>(W_ih, b_ih, b_hh, ws_f);
    k_lstm<<<256, 256, 0, stream>>>(x, W_hh, ws_f, out);
    k_fc<<<2048, 256, 0, stream>>>(fc_W, fc_b, out);
}

// Round 4
// 6280.329 us; speedup vs baseline: 2.0650x; 1.1737x over previous
//
#include <hip/hip_runtime.h>
#include <stdint.h>

#define TT 2048
#define BB 64
#define HH 256

// ws float-word layout
#define WIHT_OFF 0          // W_ih^T : 256 tokens x 1024 gate-rows
#define BIAS_OFF 262144     // b_ih + b_hh : 1024
#define HBUF_OFF 263168     // packed h exchange: u64[2][64][256] = 65536 floats
#define XMAP_OFF 328704     // 256 u32: per-WG published XCC id (0x100 | id)
#define WS_TOT   328960

#define LOGITS   33554432   // 64*2048*256

// ---------------- K1: prep (transpose W_ih, fuse biases, zero exch+xmap) ------
__global__ __launch_bounds__(256, 1) void k_prep(const float* __restrict__ W_ih,
                                                 const float* __restrict__ b_ih,
                                                 const float* __restrict__ b_hh,
                                                 float* ws_f) {
    int idx = blockIdx.x * 256 + threadIdx.x;
    if (idx < 262144) {
        int v = idx >> 10, r = idx & 1023;
        ws_f[WIHT_OFF + idx] = W_ih[r * 256 + v];
    } else if (idx < 263168) {
        int r = idx - 262144;
        ws_f[idx] = b_ih[r] + b_hh[r];
    } else if (idx < WS_TOT) {
        ws_f[idx] = 0.0f;   // exchange slots (epoch=0,val=0) + xcc map = 0
    }
}

// fast activations (no ocml branches); __expf -> v_exp_f32
__device__ __forceinline__ float sigm_f(float x) { return 1.0f / (1.0f + __expf(-x)); }
__device__ __forceinline__ float tanh_f(float x) {
    float e = __expf(2.0f * x);
    return 1.0f - 2.0f / (e + 1.0f);   // +-inf-safe: -> 1 / -1
}

// fast-path read: bypass L1, served from the (shared, same-XCD) L2.
// Correct ONLY when producer and consumer share an XCD; the sticky fallback
// below makes mis-detection non-fatal (degrades to round-2 semantics).
__device__ __forceinline__ unsigned long long ld_l2(const unsigned long long* p) {
    unsigned long long v;
    asm volatile("global_load_dwordx2 %0, %1, off sc0\n\ts_waitcnt vmcnt(0)"
                 : "=v"(v) : "v"(p) : "memory");
    return v;
}

// ---------------- K2: persistent LSTM recurrence ------------------------------
// 256 WGs x 256 threads; WG (b,q) owns hidden units [q*64,q*64+64) of batch b.
// W_hh rows in regs, column-quarters ROTATED: i in [0,48) = remote quarters in
// arrival order (hin), i in [48,64) = own quarter (hloc) computed BEFORE the
// poll. Exchange: producer stores packed (epoch<<32|bits) u64 at DEVICE scope
// (always; visible to both L2 and MALL readers). Consumers poll via sc0 L2
// reads when the XCC handshake says all 4 peers share an XCD, with a guarded
// PER-THREAD STICKY fallback to device-scope atomic loads (round-2 path).
__global__ __launch_bounds__(256, 1) void k_lstm(const int* __restrict__ x,
                                                 const float* __restrict__ W_hh,
                                                 float* ws_f,
                                                 float* out) {
    const int tid = threadIdx.x;
    const int bid = blockIdx.x;
    const int xcd  = bid & 7;
    const int slot = bid >> 3;
    const int b = xcd + 8 * (slot >> 2);
    const int q = slot & 3;
    const int u  = tid & 63;
    const int w  = tid >> 6;            // wave id = quarter it polls
    const int gt = w;                   // gate 0=i 1=f 2=g 3=o
    const int j  = q * 64 + u;
    const int r  = gt * 256 + j;        // gate row in [0,1024)

    __shared__ alignas(16) float hin[192];   // remote quarters, rotated order
    __shared__ alignas(16) float hloc[64];   // own quarter's h
    __shared__ float gbuf[256];
    __shared__ int xs[4];

    // ---- one-time: W_hh row r -> regs, column-rotated ----
    float4 w4[64];
#pragma unroll
    for (int i = 0; i < 64; ++i) {
        int cb = (i < 48) ? ((q + 1 + (i >> 4)) & 3) : q;
        int wi = (i < 48) ? (i & 15) : (i - 48);
        w4[i] = *(const float4*)(W_hh + (size_t)r * 256 + cb * 64 + wi * 4);
    }
    const float bias_r = ws_f[BIAS_OFF + r];
    unsigned long long* hbuf = (unsigned long long*)(ws_f + HBUF_OFF);
    unsigned* xmap = (unsigned*)ws_f + XMAP_OFF;
    const int* xrow = x + b * TT;
    const bool ownw = (w == q);
    const int rb = (w - q + 3) & 3;     // rotated hin slot for polled quarter

    // ---- one-time: XCC handshake (ground truth; failure -> slow mode) ----
    int myxcc = 0;
    asm volatile("s_getreg_b32 %0, hwreg(HW_REG_XCC_ID)" : "=s"(myxcc));
    if (tid == 0)
        __hip_atomic_store(&xmap[bid], 0x100u | (unsigned)myxcc,
                           __ATOMIC_RELAXED, __HIP_MEMORY_SCOPE_AGENT);
    if (tid < 4) {
        int pb = (b & 7) + 8 * ((b >> 3) * 4 + tid);
        unsigned v; int g = 0;
        do {
            v = __hip_atomic_load(&xmap[pb], __ATOMIC_RELAXED, __HIP_MEMORY_SCOPE_AGENT);
        } while (!(v & 0x100u) && ++g < (1 << 20));
        xs[tid] = (v & 0x100u) ? (int)(v & 0xffu) : -1 - tid;  // timeout -> mismatch
    }
    if (tid < 64) hloc[tid] = 0.0f;     // h(0) = 0
    float c_state = 0.0f;               // live in tid<64 (wave 0)
    __syncthreads();
    bool fastm = (xs[0] == xs[1]) & (xs[1] == xs[2]) & (xs[2] == xs[3]);

    const float4* hin4 = (const float4*)hin;
    const float4* hl4  = (const float4*)hloc;

    for (int t = 0; t < TT; ++t) {
        const int p = t & 1;
        int tok = xrow[t];
        float xw = ws_f[WIHT_OFF + tok * 1024 + r] + bias_r;

        // own-quarter partial dot from LDS — hides under the exchange latency
        float a0 = 0.f, a1 = 0.f, a2 = 0.f, a3 = 0.f;
#pragma unroll
        for (int i = 0; i < 16; ++i) {
            float4 hh = hl4[i];
            a0 += w4[48 + i].x * hh.x;
            a1 += w4[48 + i].y * hh.y;
            a2 += w4[48 + i].z * hh.z;
            a3 += w4[48 + i].w * hh.w;
        }

        // poll remote quarter (packed epoch|value), write rotated slot
        if (!ownw) {
            const unsigned long long* src = hbuf + (size_t)p * (BB * HH) + b * HH + tid;
            const unsigned ut = (unsigned)t;
            unsigned long long v = 0;
            if (fastm) {                 // shared-L2 poll, guarded
                int g = 0;
                do { v = ld_l2(src); } while ((unsigned)(v >> 32) != ut && ++g < 6000);
                if ((unsigned)(v >> 32) != ut) fastm = false;  // sticky fallback
            }
            if (!fastm) {                // round-2 proven path
                int g = 0;
                do {
                    v = __hip_atomic_load(src, __ATOMIC_RELAXED, __HIP_MEMORY_SCOPE_AGENT);
                } while ((unsigned)(v >> 32) != ut && ++g < (1 << 21));
            }
            hin[rb * 64 + u] = __uint_as_float((unsigned)v);
        }
        __syncthreads();

        // remaining 3 quarters, branch-free (rotation did the index mapping)
#pragma unroll
        for (int i = 0; i < 48; ++i) {
            float4 hh = hin4[i];
            a0 += w4[i].x * hh.x;
            a1 += w4[i].y * hh.y;
            a2 += w4[i].z * hh.z;
            a3 += w4[i].w * hh.w;
        }
        float gate = xw + ((a0 + a1) + (a2 + a3));
        float act = (gt == 2) ? tanh_f(gate) : sigm_f(gate);  // wave-uniform
        gbuf[tid] = act;
        __syncthreads();

        if (tid < 64) {                  // wave 0 combines gates, owns c
            float ig = gbuf[tid], fg = gbuf[64 + tid];
            float gg = gbuf[128 + tid], og = gbuf[192 + tid];
            c_state = fg * c_state + ig * gg;
            float hval = og * tanh_f(c_state);
            // critical-path store first: device scope ALWAYS (feeds both the
            // peers' shared-L2 reads and any fallen-back MALL readers)
            unsigned long long pv =
                ((unsigned long long)(unsigned)(t + 1) << 32) |
                (unsigned long long)__float_as_uint(hval);
            __hip_atomic_store(hbuf + (size_t)((t + 1) & 1) * (BB * HH) + b * HH + j,
                               pv, __ATOMIC_RELAXED, __HIP_MEMORY_SCOPE_AGENT);
            hloc[tid] = hval;
            out[((size_t)(b * TT + t) << 8) + j] = hval;             // h history
            if (t == TT - 1) {
                out[LOGITS + b * HH + j] = hval;                     // h_n
                out[LOGITS + BB * HH + b * HH + j] = c_state;        // c_n
            }
        }
        __syncthreads();                 // protects hloc/gbuf/hin for next iter
    }
}

// ---------------- K3: FC epilogue, in-place over the logits region ------------
__global__ __launch_bounds__(256, 1) void k_fc(const float* __restrict__ fc_W,
                                               const float* __restrict__ fc_b,
                                               float* out) {
    __shared__ alignas(16) float ht[64][256];
    const int tid = threadIdx.x;
    const size_t base = (size_t)blockIdx.x * 64;
    for (int i = 0; i < 64; ++i)
        ht[i][tid] = out[(base + i) * 256 + tid];

    float4 w4[64];
    const float4* wr = (const float4*)(fc_W + (size_t)tid * 256);
#pragma unroll
    for (int k = 0; k < 64; ++k) w4[k] = wr[k];
    const float bias = fc_b[tid];
    __syncthreads();

    for (int m = 0; m < 64; ++m) {
        const float4* hv = (const float4*)ht[m];
        float a0 = 0.f, a1 = 0.f, a2 = 0.f, a3 = 0.f;
#pragma unroll
        for (int k = 0; k < 64; ++k) {
            float4 hh = hv[k];
            a0 += w4[k].x * hh.x;
            a1 += w4[k].y * hh.y;
            a2 += w4[k].z * hh.z;
            a3 += w4[k].w * hh.w;
        }
        out[(base + m) * 256 + tid] = bias + ((a0 + a1) + (a2 + a3));
    }
}

// ---------------- launch ------------------------------------------------------
extern "C" void kernel_launch(void* const* d_in, const int* in_sizes, int n_in,
                              void* d_out, int out_size, void* d_ws, size_t ws_size,
                              hipStream_t stream) {
    const int*   x    = (const int*)d_in[0];
    const float* W_ih = (const float*)d_in[1];
    const float* W_hh = (const float*)d_in[2];
    const float* b_ih = (const float*)d_in[3];
    const float* b_hh = (const float*)d_in[4];
    const float* fc_W = (const float*)d_in[5];
    const float* fc_b = (const float*)d_in[6];
    float* out  = (float*)d_out;
    float* ws_f = (float*)d_ws;

    k_prep<<<(WS_TOT + 255) / 256, 256, 0, stream>>>(W_ih, b_ih, b_hh, ws_f);
    k_lstm<<<256, 256, 0, stream>>>(x, W_hh, ws_f, out);
    k_fc<<<2048, 256, 0, stream>>>(fc_W, fc_b, out);
}